// Round 15
// baseline (31.937 us; speedup 1.0000x reference)
//
#include <hip/hip_runtime.h>
#include <type_traits>

#define IMG_W 256
#define IMG_H 256
#define EPSN 1e-7f
#define NS 50.0f            // 1/(2*0.1^2)
#define NB 16
#define NN 64
#define NC 3
#define PH 32
#define PW 32
#define NWG 2048            // 128 tiles/image * 16 images

// One block per 32x16 tile, 192 threads (3c x 8ysub x 8xgrp), thread owns
// 4x x 2y. Stroke loop: 2 strokes per iteration, branchless lane masking
// (mask folded into hoisted W weights), all 30 loads issued before the
// register-only M-switches -> both strokes' L1/L2 latencies overlap.
__global__ __launch_bounds__(192)
void fused_kernel(const float* __restrict__ brushes,
                  const float* __restrict__ patches,
                  float* __restrict__ out) {
    __shared__ float2 sG[NN];       // gx, gy
    __shared__ int    sN[NN];       // stroke index
    __shared__ int    sPb[NN];      // pbase (block-uniform per stroke)
    __shared__ float  sSx[NN];      // x lattice sum (rare edge fix)
    __shared__ float4 sWx[NN];      // normalized x weights
    __shared__ float4 sEyC[NN];     // Ey * DyC  (incl. 1/N)
    __shared__ float4 sEy31[NN];    // Ey * Dy31 (incl. 1/N)
    __shared__ int    sCnt;

    // XCD-contiguous swizzle: each XCD owns 256 consecutive tiles = 2 images
    int blk = blockIdx.x;
    blk = (blk & 7) * (NWG >> 3) + (blk >> 3);

    const int b    = blk >> 7;
    const int t7   = blk & 127;
    const int ty0  = (t7 >> 3) * 16;            // 16 y-tiles
    const int tx0  = (t7 & 7) * 32;             // 8 x-tiles
    const int tid  = threadIdx.x;
    const int cc   = tid >> 6;
    const int lane = tid & 63;
    const int ysub = lane >> 3;                 // y rows 2*ysub, 2*ysub+1
    const int xgrp = lane & 7;                  // x group of 4
    const int ax0  = tx0 + xgrp * 4;
    const int ay0  = ty0 + ysub * 2;

    // --- wave 0: norm + ballot overlap list + per-stroke weight precompute ---
    if (tid < 64) {
        float2 v = ((const float2*)brushes)[b * NN + tid];
        float mnx = v.x, mxx = v.x, mny = v.y, mxy = v.y;
        #pragma unroll
        for (int off = 32; off > 0; off >>= 1) {
            mnx = fminf(mnx, __shfl_xor(mnx, off));
            mxx = fmaxf(mxx, __shfl_xor(mxx, off));
            mny = fminf(mny, __shfl_xor(mny, off));
            mxy = fmaxf(mxy, __shfl_xor(mxy, off));
        }
        float gx = (v.x - mnx) / (mxx - mnx + EPSN) * (float)IMG_W;
        float gy = (v.y - mny) / (mxy - mny + EPSN) * (float)IMG_H;
        int ix0 = (int)floorf(gx) - 17;
        int iy0 = (int)floorf(gy) - 17;
        bool ov = (ix0 <= tx0 + 31) && (ix0 + 35 >= tx0) &&
                  (iy0 <= ty0 + 15) && (iy0 + 35 >= ty0);
        unsigned long long mask = __ballot(ov);
        if (ov) {
            int pos = __popcll(mask & ((1ull << tid) - 1));
            sN[pos] = tid;
            sG[pos] = make_float2(gx, gy);

            float px  = 15.5f - gx;             // phx stroke-pure (ax0 % 4 == 0)
            float phx = px - floorf(px);
            float Ex[4];
            #pragma unroll
            for (int k = 0; k < 4; ++k) {
                float d = phx + (float)(1 - k);
                Ex[k] = __expf(-NS * d * d);
            }
            float Sx  = ((Ex[0] + Ex[1]) + (Ex[2] + Ex[3]));
            float Dxc = 1.f / (Sx + EPSN);
            sSx[pos] = Sx;
            sWx[pos] = make_float4(Ex[0] * Dxc, Ex[1] * Dxc,
                                   Ex[2] * Dxc, Ex[3] * Dxc);

            float zy0 = (float)ty0 - gy + 15.4f;
            float fz  = floorf(zy0);
            sPb[pos]  = (int)fz - 1;
            float psy = zy0 - fz;
            float Ey[4];
            #pragma unroll
            for (int k = 0; k < 4; ++k) {
                float d = psy + (float)(1 - k);
                Ey[k] = __expf(-NS * d * d);
            }
            float Sy  = ((Ey[0] + Ey[1]) + (Ey[2] + Ey[3]));
            float DyC = (1.f / (Sy + EPSN)) * (1.0f / (float)NN);
            float Dy31 = DyC;
            if (gy > 254.9f) {
                float cy31 = gy + 15.6f;
                float dc   = 272.f - cy31;
                float c272 = __expf(-NS * dc * dc);
                Dy31 = (1.f / (Sy - c272 + EPSN)) * (1.0f / (float)NN);
            }
            sEyC[pos]  = make_float4(Ey[0] * DyC,  Ey[1] * DyC,
                                     Ey[2] * DyC,  Ey[3] * DyC);
            sEy31[pos] = make_float4(Ey[0] * Dy31, Ey[1] * Dy31,
                                     Ey[2] * Dy31, Ey[3] * Dy31);
        }
        if (tid == 0) sCnt = (int)__popcll(mask);
    }
    __syncthreads();                            // only barrier in the kernel
    const int cnt = sCnt;

    float acc[2][4];
    #pragma unroll
    for (int j = 0; j < 2; ++j)
        #pragma unroll
        for (int o = 0; o < 4; ++o) acc[j][o] = 0.f;

    const float* Pcb = patches + (size_t)b * NN * (NC * PH * PW) + cc * (PH * PW);

    // per-stroke meta (branchless; lane-activity folded into W)
    struct Meta {
        const float* Pc;
        float W[4];
        float m0, m1, m2;
        int c0, c1, c2, M, pb;
        float zx0, gx, sv;                      // sv = slot-valid
    };
    auto mkMeta = [&](int idx, float sv) {
        Meta m;
        const float2 g = sG[idx];
        m.gx = g.x;
        m.Pc = Pcb + (size_t)sN[idx] * (NC * PH * PW);
        m.zx0 = (float)ax0 - g.x + 15.5f;
        int q00 = (int)floorf(m.zx0) - 1;
        float act = (q00 >= -6 && q00 <= 31) ? sv : 0.f;
        float4 W4 = sWx[idx];
        m.W[0] = W4.x * act; m.W[1] = W4.y * act;
        m.W[2] = W4.z * act; m.W[3] = W4.w * act;
        int qg = ((q00 + 8) & ~3) - 8;
        m.M  = (q00 + 8) & 3;
        int s1 = qg + 4, s2 = qg + 8;
        m.m0 = (qg >= 0 && qg <= 28) ? 1.f : 0.f;
        m.m1 = (s1 >= 0 && s1 <= 28) ? 1.f : 0.f;
        m.m2 = (s2 >= 0 && s2 <= 28) ? 1.f : 0.f;
        m.c0 = min(max(qg, 0), 28);
        m.c1 = min(max(s1, 0), 28);
        m.c2 = min(max(s2, 0), 28);
        m.pb = sPb[idx];
        m.sv = sv;
        return m;
    };

    auto doFMA = [&](const Meta& m, const float4 L[5][3], float t[5][4],
                     auto Mc) {
        constexpr int Mv = Mc.value;
        #pragma unroll
        for (int rr = 0; rr < 5; ++rr) {
            float4 A  = L[rr][0];
            float4 Bv = L[rr][1];
            float4 Cv = L[rr][2];
            float pv[12] = {A.x * m.m0,  A.y * m.m0,  A.z * m.m0,  A.w * m.m0,
                            Bv.x * m.m1, Bv.y * m.m1, Bv.z * m.m1, Bv.w * m.m1,
                            Cv.x * m.m2, Cv.y * m.m2, Cv.z * m.m2, Cv.w * m.m2};
            #pragma unroll
            for (int o = 0; o < 4; ++o)
                t[rr][o] = m.W[0] * pv[Mv + o]     + m.W[1] * pv[Mv + o + 1]
                         + m.W[2] * pv[Mv + o + 2] + m.W[3] * pv[Mv + o + 3];
        }
    };

    auto edgeFix = [&](const Meta& m, float Sx_, float t[5][4]) {
        // rare: a=272 clipped for tap q=31; e31 self-gates for far lanes
        float Dxc_ = 1.f / (Sx_ + EPSN);
        float cx31 = m.gx + 15.5f;
        float dc   = 272.f - cx31;
        float c272 = __expf(-NS * dc * dc);
        float dD   = (1.f / (Sx_ - c272 + EPSN) - Dxc_) * m.sv;
        float e31[4];
        #pragma unroll
        for (int o = 0; o < 4; ++o) {
            float d = m.zx0 + (float)o - 31.f;
            e31[o] = __expf(-NS * d * d) * dD;
        }
        #pragma unroll
        for (int rr = 0; rr < 5; ++rr) {
            int src = min(max(m.pb + 2 * ysub + rr, 0), 31);
            float p31 = m.Pc[(src << 5) + 31];
            #pragma unroll
            for (int o = 0; o < 4; ++o) t[rr][o] += e31[o] * p31;
        }
    };

    auto yCombine = [&](const Meta& m, int idx, const float t[5][4]) {
        const float4 eC = sEyC[idx];
        const float4 e3 = sEy31[idx];
        const float eyC[4]  = {eC.x, eC.y, eC.z, eC.w};
        const float ey31[4] = {e3.x, e3.y, e3.z, e3.w};
        float wyA[4], wyB[4];
        #pragma unroll
        for (int k = 0; k < 4; ++k) {
            int rA = m.pb + 2 * ysub + k;
            int rB = rA + 1;
            wyA[k] = ((unsigned)rA < 32u) ? ((rA == 31) ? ey31[k] : eyC[k]) : 0.f;
            wyB[k] = ((unsigned)rB < 32u) ? ((rB == 31) ? ey31[k] : eyC[k]) : 0.f;
        }
        #pragma unroll
        for (int o = 0; o < 4; ++o) {
            acc[0][o] += wyA[0] * t[0][o] + wyA[1] * t[1][o]
                       + wyA[2] * t[2][o] + wyA[3] * t[3][o];
            acc[1][o] += wyB[0] * t[1][o] + wyB[1] * t[2][o]
                       + wyB[2] * t[3][o] + wyB[3] * t[4][o];
        }
    };

    auto loadRows = [&](const Meta& m, float4 L[5][3]) {
        #pragma unroll
        for (int rr = 0; rr < 5; ++rr) {
            int src = min(max(m.pb + 2 * ysub + rr, 0), 31);
            const float* rp = m.Pc + (src << 5);
            L[rr][0] = *(const float4*)(rp + m.c0);
            L[rr][1] = *(const float4*)(rp + m.c1);
            L[rr][2] = *(const float4*)(rp + m.c2);
        }
    };

    for (int i = 0; i < cnt; i += 2) {
        const int   has2 = (i + 1 < cnt);
        const int   iB   = has2 ? i + 1 : i;
        const Meta  mA = mkMeta(i,  1.f);
        const Meta  mB = mkMeta(iB, has2 ? 1.f : 0.f);

        // ---- all 30 loads issued before any FMA-switch ----
        float4 LA[5][3], LB[5][3];
        loadRows(mA, LA);
        loadRows(mB, LB);

        float tA[5][4], tB[5][4];
        switch (mA.M) {
            case 0: doFMA(mA, LA, tA, std::integral_constant<int, 0>{}); break;
            case 1: doFMA(mA, LA, tA, std::integral_constant<int, 1>{}); break;
            case 2: doFMA(mA, LA, tA, std::integral_constant<int, 2>{}); break;
            default: doFMA(mA, LA, tA, std::integral_constant<int, 3>{}); break;
        }
        if (mA.gx > 255.0f) edgeFix(mA, sSx[i], tA);
        yCombine(mA, i, tA);

        switch (mB.M) {
            case 0: doFMA(mB, LB, tB, std::integral_constant<int, 0>{}); break;
            case 1: doFMA(mB, LB, tB, std::integral_constant<int, 1>{}); break;
            case 2: doFMA(mB, LB, tB, std::integral_constant<int, 2>{}); break;
            default: doFMA(mB, LB, tB, std::integral_constant<int, 3>{}); break;
        }
        if (mB.gx > 255.0f && has2) edgeFix(mB, sSx[iB], tB);
        yCombine(mB, iB, tB);
    }

    // coalesced float4 stores; tiles partition the image
    #pragma unroll
    for (int j = 0; j < 2; ++j) {
        float* o = out + (((size_t)b * NC + cc) * IMG_H + ay0 + j) * IMG_W + ax0;
        *(float4*)o = make_float4(acc[j][0], acc[j][1], acc[j][2], acc[j][3]);
    }
}

extern "C" void kernel_launch(void* const* d_in, const int* in_sizes, int n_in,
                              void* d_out, int out_size, void* d_ws, size_t ws_size,
                              hipStream_t stream) {
    const float* brushes = (const float*)d_in[0];   // (16, 64, 2) f32
    const float* patches = (const float*)d_in[1];   // (16, 64, 3, 32, 32) f32
    float* out = (float*)d_out;                     // (16, 3, 256, 256) f32

    fused_kernel<<<NWG, 192, 0, stream>>>(brushes, patches, out);
}

// Round 16
// 24.079 us; speedup vs baseline: 1.3263x; 1.3263x over previous
//
#include <hip/hip_runtime.h>
#include <type_traits>

#define IMG_W 256
#define IMG_H 256
#define EPSN 1e-7f
#define NS 50.0f            // 1/(2*0.1^2)
#define NB 16
#define NN 64
#define NC 3
#define PH 32
#define PW 32
#define NWG 2048            // 128 tiles/image * 16 images

// One block per 32x16 tile, 192 threads (3c x 8ysub x 8xgrp), thread owns
// 4x x 2y. Verified R13 structure + register slimming: row contributions
// stream directly into acc (no t[5][4] array) -> shorter live ranges,
// lower VGPR, more resident waves for latency hiding.
__global__ __launch_bounds__(192)
void fused_kernel(const float* __restrict__ brushes,
                  const float* __restrict__ patches,
                  float* __restrict__ out) {
    __shared__ float2 sG[NN];       // gx, gy
    __shared__ int    sN[NN];       // stroke index
    __shared__ int    sPb[NN];      // pbase (block-uniform per stroke)
    __shared__ float  sSx[NN];      // x lattice sum (rare edge fix)
    __shared__ float4 sWx[NN];      // normalized x weights
    __shared__ float4 sEyC[NN];     // Ey * DyC  (incl. 1/N)
    __shared__ float4 sEy31[NN];    // Ey * Dy31 (incl. 1/N)
    __shared__ int    sCnt;

    // XCD-contiguous swizzle: each XCD owns 256 consecutive tiles = 2 images
    int blk = blockIdx.x;
    blk = (blk & 7) * (NWG >> 3) + (blk >> 3);

    const int b    = blk >> 7;
    const int t7   = blk & 127;
    const int ty0  = (t7 >> 3) * 16;            // 16 y-tiles
    const int tx0  = (t7 & 7) * 32;             // 8 x-tiles
    const int tid  = threadIdx.x;
    const int cc   = tid >> 6;
    const int lane = tid & 63;
    const int ysub = lane >> 3;                 // y rows 2*ysub, 2*ysub+1
    const int xgrp = lane & 7;                  // x group of 4
    const int ax0  = tx0 + xgrp * 4;
    const int ay0  = ty0 + ysub * 2;

    // --- wave 0: norm + ballot overlap list + per-stroke weight precompute ---
    if (tid < 64) {
        float2 v = ((const float2*)brushes)[b * NN + tid];
        float mnx = v.x, mxx = v.x, mny = v.y, mxy = v.y;
        #pragma unroll
        for (int off = 32; off > 0; off >>= 1) {
            mnx = fminf(mnx, __shfl_xor(mnx, off));
            mxx = fmaxf(mxx, __shfl_xor(mxx, off));
            mny = fminf(mny, __shfl_xor(mny, off));
            mxy = fmaxf(mxy, __shfl_xor(mxy, off));
        }
        float gx = (v.x - mnx) / (mxx - mnx + EPSN) * (float)IMG_W;
        float gy = (v.y - mny) / (mxy - mny + EPSN) * (float)IMG_H;
        int ix0 = (int)floorf(gx) - 17;
        int iy0 = (int)floorf(gy) - 17;
        bool ov = (ix0 <= tx0 + 31) && (ix0 + 35 >= tx0) &&
                  (iy0 <= ty0 + 15) && (iy0 + 35 >= ty0);
        unsigned long long mask = __ballot(ov);
        if (ov) {
            int pos = __popcll(mask & ((1ull << tid) - 1));
            sN[pos] = tid;
            sG[pos] = make_float2(gx, gy);

            // x weights: phx = frac(zx0) is stroke-pure (ax0 % 4 == 0)
            float px  = 15.5f - gx;
            float phx = px - floorf(px);
            float Ex[4];
            #pragma unroll
            for (int k = 0; k < 4; ++k) {
                float d = phx + (float)(1 - k);
                Ex[k] = __expf(-NS * d * d);
            }
            float Sx  = ((Ex[0] + Ex[1]) + (Ex[2] + Ex[3]));
            float Dxc = 1.f / (Sx + EPSN);
            sSx[pos] = Sx;
            sWx[pos] = make_float4(Ex[0] * Dxc, Ex[1] * Dxc,
                                   Ex[2] * Dxc, Ex[3] * Dxc);

            // y weights: zy0 block-uniform
            float zy0 = (float)ty0 - gy + 15.4f;
            float fz  = floorf(zy0);
            sPb[pos]  = (int)fz - 1;
            float psy = zy0 - fz;
            float Ey[4];
            #pragma unroll
            for (int k = 0; k < 4; ++k) {
                float d = psy + (float)(1 - k);
                Ey[k] = __expf(-NS * d * d);
            }
            float Sy  = ((Ey[0] + Ey[1]) + (Ey[2] + Ey[3]));
            float DyC = (1.f / (Sy + EPSN)) * (1.0f / (float)NN);
            float Dy31 = DyC;
            if (gy > 254.9f) {                  // b=272 clipped for tap row 31
                float cy31 = gy + 15.6f;
                float dc   = 272.f - cy31;
                float c272 = __expf(-NS * dc * dc);
                Dy31 = (1.f / (Sy - c272 + EPSN)) * (1.0f / (float)NN);
            }
            sEyC[pos]  = make_float4(Ey[0] * DyC,  Ey[1] * DyC,
                                     Ey[2] * DyC,  Ey[3] * DyC);
            sEy31[pos] = make_float4(Ey[0] * Dy31, Ey[1] * Dy31,
                                     Ey[2] * Dy31, Ey[3] * Dy31);
        }
        if (tid == 0) sCnt = (int)__popcll(mask);
    }
    __syncthreads();                            // only barrier in the kernel
    const int cnt = sCnt;

    float acc[2][4];
    #pragma unroll
    for (int j = 0; j < 2; ++j)
        #pragma unroll
        for (int o = 0; o < 4; ++o) acc[j][o] = 0.f;

    const float* Pcb = patches + (size_t)b * NN * (NC * PH * PW) + cc * (PH * PW);

    for (int i = 0; i < cnt; ++i) {
        const float2 g = sG[i];                 // LDS broadcast
        const int    n = sN[i];
        const float* Pc = Pcb + (size_t)n * (NC * PH * PW);

        const float zx0 = (float)ax0 - g.x + 15.5f;
        const int   q00 = (int)floorf(zx0) - 1;

        if (q00 >= -6 && q00 <= 31) {           // proven active window
            const float4 W4 = sWx[i];           // broadcast
            const float  W[4] = {W4.x, W4.y, W4.z, W4.w};
            const int    pb = sPb[i];

            // y weights (needed inside the streaming row loop)
            const float4 eC = sEyC[i];
            const float4 e3 = sEy31[i];
            const float eyC[4]  = {eC.x, eC.y, eC.z, eC.w};
            const float ey31[4] = {e3.x, e3.y, e3.z, e3.w};
            float wyA[4], wyB[4];
            #pragma unroll
            for (int k = 0; k < 4; ++k) {
                int rA = pb + 2 * ysub + k;
                int rB = rA + 1;
                wyA[k] = ((unsigned)rA < 32u) ? ((rA == 31) ? ey31[k] : eyC[k]) : 0.f;
                wyB[k] = ((unsigned)rB < 32u) ? ((rB == 31) ? ey31[k] : eyC[k]) : 0.f;
            }

            const int qg = ((q00 + 8) & ~3) - 8;    // [-8,28], multiple of 4
            const int M  = (q00 + 8) & 3;           // wave-uniform per stroke
            const int s1 = qg + 4, s2 = qg + 8;
            const float m0 = (qg >= 0 && qg <= 28) ? 1.f : 0.f;
            const float m1 = (s1 >= 0 && s1 <= 28) ? 1.f : 0.f;
            const float m2 = (s2 >= 0 && s2 <= 28) ? 1.f : 0.f;
            const int c0 = min(max(qg, 0), 28);
            const int c1 = min(max(s1, 0), 28);
            const int c2 = min(max(s2, 0), 28);

            // streaming rows: x-filter row rr -> immediately fold into acc
            auto rows = [&](auto Mc) {
                constexpr int Mv = Mc.value;
                #pragma unroll
                for (int rr = 0; rr < 5; ++rr) {
                    int src = min(max(pb + 2 * ysub + rr, 0), 31);
                    const float* rp = Pc + (src << 5);
                    float4 A  = *(const float4*)(rp + c0);
                    float4 Bv = *(const float4*)(rp + c1);
                    float cx0 = 0.f, cx1 = 0.f, cx2 = 0.f, cx3 = 0.f;
                    if constexpr (Mv >= 2) {    // chunk C statically dead for M<2
                        float4 Cv = *(const float4*)(rp + c2);
                        cx0 = Cv.x * m2; cx1 = Cv.y * m2;
                        cx2 = Cv.z * m2; cx3 = Cv.w * m2;
                    }
                    float pv[12] = {A.x * m0, A.y * m0, A.z * m0, A.w * m0,
                                    Bv.x * m1, Bv.y * m1, Bv.z * m1, Bv.w * m1,
                                    cx0, cx1, cx2, cx3};
                    float tr[4];
                    #pragma unroll
                    for (int o = 0; o < 4; ++o)
                        tr[o] = W[0] * pv[Mv + o]     + W[1] * pv[Mv + o + 1]
                              + W[2] * pv[Mv + o + 2] + W[3] * pv[Mv + o + 3];
                    if (rr < 4) {               // static after unroll
                        #pragma unroll
                        for (int o = 0; o < 4; ++o) acc[0][o] += wyA[rr] * tr[o];
                    }
                    if (rr >= 1) {
                        #pragma unroll
                        for (int o = 0; o < 4; ++o) acc[1][o] += wyB[rr - 1] * tr[o];
                    }
                }
            };
            switch (M) {
                case 0: rows(std::integral_constant<int, 0>{}); break;
                case 1: rows(std::integral_constant<int, 1>{}); break;
                case 2: rows(std::integral_constant<int, 2>{}); break;
                default: rows(std::integral_constant<int, 3>{}); break;
            }

            // --- rare x boundary-denominator fix (a=272 clipped, tap 31) ---
            if (g.x > 255.0f) {
                float Sx_  = sSx[i];
                float Dxc_ = 1.f / (Sx_ + EPSN);
                float cx31 = g.x + 15.5f;
                float dc   = 272.f - cx31;
                float c272 = __expf(-NS * dc * dc);
                float dD   = 1.f / (Sx_ - c272 + EPSN) - Dxc_;
                float e31[4];
                #pragma unroll
                for (int o = 0; o < 4; ++o) {
                    float d = zx0 + (float)o - 31.f;
                    e31[o] = __expf(-NS * d * d) * dD;  // self-gating (0 if far)
                }
                #pragma unroll
                for (int rr = 0; rr < 5; ++rr) {
                    int src = min(max(pb + 2 * ysub + rr, 0), 31);
                    float p31 = Pc[(src << 5) + 31];
                    float ta[4];
                    #pragma unroll
                    for (int o = 0; o < 4; ++o) ta[o] = e31[o] * p31;
                    if (rr < 4) {
                        #pragma unroll
                        for (int o = 0; o < 4; ++o) acc[0][o] += wyA[rr] * ta[o];
                    }
                    if (rr >= 1) {
                        #pragma unroll
                        for (int o = 0; o < 4; ++o) acc[1][o] += wyB[rr - 1] * ta[o];
                    }
                }
            }
        }
    }

    // coalesced float4 stores; tiles partition the image
    #pragma unroll
    for (int j = 0; j < 2; ++j) {
        float* o = out + (((size_t)b * NC + cc) * IMG_H + ay0 + j) * IMG_W + ax0;
        *(float4*)o = make_float4(acc[j][0], acc[j][1], acc[j][2], acc[j][3]);
    }
}

extern "C" void kernel_launch(void* const* d_in, const int* in_sizes, int n_in,
                              void* d_out, int out_size, void* d_ws, size_t ws_size,
                              hipStream_t stream) {
    const float* brushes = (const float*)d_in[0];   // (16, 64, 2) f32
    const float* patches = (const float*)d_in[1];   // (16, 64, 3, 32, 32) f32
    float* out = (float*)d_out;                     // (16, 3, 256, 256) f32

    fused_kernel<<<NWG, 192, 0, stream>>>(brushes, patches, out);
}